// Round 10
// baseline (261.035 us; speedup 1.0000x reference)
//
#include <hip/hip_runtime.h>
#include <hip/hip_bf16.h>
#include <stdint.h>

typedef __attribute__((ext_vector_type(8))) short short8;
typedef __attribute__((ext_vector_type(4))) short short4v;
typedef __attribute__((ext_vector_type(4))) float f32x4;

#define MFMA(a, b, c) __builtin_amdgcn_mfma_f32_16x16x32_bf16((a), (b), (c), 0, 0, 0)

#define C1 0.18033688011112042f   // 0.125 * log2(e)
#define INV_C1 5.545177444479562f // 8 * ln(2)

// packed fp32x2 -> bf16x2 (RNE); union pun is sanctioned in Clang
static __device__ __forceinline__ unsigned int f2bf2(float x, float y) {
  union { __hip_bfloat162 h; unsigned int u; } c;
  c.h = __float22bfloat162_rn(make_float2(x, y));
  return c.u;
}
static __device__ __forceinline__ short f2bf(float f) {
  return (short)(f2bf2(f, 0.0f) & 0xffffu);
}
static __device__ __forceinline__ float bf2f(short u) {
  union { unsigned int i; float f; } c;
  c.i = ((unsigned int)(unsigned short)u) << 16;
  return c.f;
}

// int-ordered max on non-negative floats; ws poison (negative int) = identity
static __device__ __forceinline__ void atomic_max_f32(float* addr, float v) {
  atomicMax((int*)addr, __float_as_int(v));
}

// ---------------- one-shot fp32 -> bf16 conversion of X, Wq, Wk, Wv --------
__global__ __launch_bounds__(256) void k_cvt(
    const float* __restrict__ X, const float* __restrict__ Wq,
    const float* __restrict__ Wk, const float* __restrict__ Wv,
    short* __restrict__ Xb, short* __restrict__ Wb) {
  const int y = blockIdx.y;
  const float* src;
  short* dst;
  int n;
  if (y == 0) {
    src = X; dst = Xb; n = 4096 * 1024;
  } else {
    src = (y == 1) ? Wq : (y == 2) ? Wk : Wv;
    dst = Wb + (y - 1) * 1048576;
    n = 1048576;
  }
  const int i = (blockIdx.x * 256 + threadIdx.x) * 8;
  if (i >= n) return;
  const float4 a = *(const float4*)(src + i);
  const float4 b = *(const float4*)(src + i + 4);
  union { unsigned int u[4]; short8 s; } P;
  P.u[0] = f2bf2(a.x, a.y);
  P.u[1] = f2bf2(a.z, a.w);
  P.u[2] = f2bf2(b.x, b.y);
  P.u[3] = f2bf2(b.z, b.w);
  *(short8*)(dst + i) = P.s;
}

// ---------------- QKV projection: Y = X @ W^T + b (bf16 inputs) ------------
// Q is stored PRE-SCALED by C1 = 0.125*log2e so attention MFMA emits the
// exp2-domain score directly (q_max stat uses the unscaled value).
__global__ __launch_bounds__(256) void k_qkv(
    const short* __restrict__ Xb, const short* __restrict__ Wball,
    const float* __restrict__ bq, const float* __restrict__ bk,
    const float* __restrict__ bv,
    short* __restrict__ Qo, short* __restrict__ Ko, short* __restrict__ Vo,
    float* __restrict__ stats) {
  const int z = blockIdx.z;
  const short* W = Wball + z * 1048576;
  const float* bias = (z == 0) ? bq : (z == 1) ? bk : bv;
  short* out = (z == 0) ? Qo : (z == 1) ? Ko : Vo;
  const float qscale = (z == 0) ? C1 : 1.0f;

  __shared__ __align__(16) short As[128 * 32];
  __shared__ __align__(16) short Bs[128 * 32];
  __shared__ __align__(16) short Tb[4][16 * 72];
  __shared__ float red[4];

  const int t = threadIdx.x;
  const int lane = t & 63;
  const int w = t >> 6;
  const int l16 = lane & 15, quad = lane >> 4;
  const int wr = (w >> 1) * 64, wc = (w & 1) * 64;
  const int row0 = blockIdx.y * 128;
  const int col0 = blockIdx.x * 128;

  const int srow = t >> 1;
  const int scol = (t & 1) * 16;

  f32x4 acc[4][4];
#pragma unroll
  for (int i = 0; i < 4; ++i)
#pragma unroll
    for (int j = 0; j < 4; ++j) acc[i][j] = {0.f, 0.f, 0.f, 0.f};

  const short* ag = Xb + (row0 + srow) * 1024 + scol;
  const short* bg = W + (col0 + srow) * 1024 + scol;
  short* al = &As[srow * 32 + scol];
  short* bl = &Bs[srow * 32 + scol];

  short8 pa0 = *(const short8*)(ag);
  short8 pa1 = *(const short8*)(ag + 8);
  short8 pb0 = *(const short8*)(bg);
  short8 pb1 = *(const short8*)(bg + 8);

  for (int kk = 0; kk < 32; ++kk) {
    __syncthreads();
    *(short8*)(al) = pa0;
    *(short8*)(al + 8) = pa1;
    *(short8*)(bl) = pb0;
    *(short8*)(bl + 8) = pb1;
    if (kk < 31) {
      const int k0 = (kk + 1) * 32;
      pa0 = *(const short8*)(ag + k0);
      pa1 = *(const short8*)(ag + k0 + 8);
      pb0 = *(const short8*)(bg + k0);
      pb1 = *(const short8*)(bg + k0 + 8);
    }
    __syncthreads();
    short8 af[4], bf8[4];
#pragma unroll
    for (int i = 0; i < 4; ++i)
      af[i] = *(const short8*)&As[(wr + i * 16 + l16) * 32 + quad * 8];
#pragma unroll
    for (int j = 0; j < 4; ++j)
      bf8[j] = *(const short8*)&Bs[(wc + j * 16 + l16) * 32 + quad * 8];
#pragma unroll
    for (int i = 0; i < 4; ++i)
#pragma unroll
      for (int j = 0; j < 4; ++j) acc[i][j] = MFMA(af[i], bf8[j], acc[i][j]);
  }

  float amax = 0.f;
  if (z < 2) {
#pragma unroll
    for (int j = 0; j < 4; ++j) {
      const int n_g = col0 + wc + j * 16 + l16;
      const float bvf = bias[n_g];
      const int h = n_g >> 6, d = n_g & 63;
#pragma unroll
      for (int i = 0; i < 4; ++i) {
        const int m_base = row0 + wr + i * 16 + quad * 4;
#pragma unroll
        for (int r = 0; r < 4; ++r) {
          const int m_g = m_base + r;
          const float y = acc[i][j][r] + bvf;
          amax = fmaxf(amax, fabsf(y));
          const int bidx = m_g >> 11, s = m_g & 2047;
          out[(((bidx << 4) | h) * 2048 + s) * 64 + d] = f2bf(y * qscale);
        }
      }
    }
  } else {
    short* Tw = &Tb[w][0];
#pragma unroll
    for (int j = 0; j < 4; ++j) {
      const int n_g = col0 + wc + j * 16 + l16;
      const float bvf = bias[n_g];
#pragma unroll
      for (int i = 0; i < 4; ++i) {
        const float y0 = acc[i][j][0] + bvf;
        const float y1 = acc[i][j][1] + bvf;
        const float y2 = acc[i][j][2] + bvf;
        const float y3 = acc[i][j][3] + bvf;
        amax = fmaxf(amax, fmaxf(fmaxf(fabsf(y0), fabsf(y1)), fmaxf(fabsf(y2), fabsf(y3))));
        union { unsigned int u[2]; short4v s; } pk;
        pk.u[0] = f2bf2(y0, y1);
        pk.u[1] = f2bf2(y2, y3);
        *(short4v*)&Tw[l16 * 72 + i * 16 + quad * 4] = pk.s;
      }
      asm volatile("" ::: "memory");
      const int c = lane >> 2;
      const int tb = lane & 3;
      short8 u0 = *(const short8*)&Tw[c * 72 + tb * 16];
      short8 u1 = *(const short8*)&Tw[c * 72 + tb * 16 + 8];
      const int col_g = col0 + wc + j * 16 + c;
      const int h = col_g >> 6, d = col_g & 63;
      const int tok0 = row0 + wr + tb * 16;
      const int bidx = tok0 >> 11, s0 = tok0 & 2047;
      short* dst = &out[(size_t)(((bidx << 4) | h) * 64 + d) * 2048 + s0];
      *(short8*)dst = u0;
      *(short8*)(dst + 8) = u1;
      asm volatile("" ::: "memory");
    }
  }
#pragma unroll
  for (int off = 32; off > 0; off >>= 1)
    amax = fmaxf(amax, __shfl_xor(amax, off, 64));
  if (lane == 0) red[w] = amax;
  __syncthreads();
  if (t == 0) {
    float m = fmaxf(fmaxf(red[0], red[1]), fmaxf(red[2], red[3]));
    atomic_max_f32(&stats[z], m);
  }
}

// ---------------- flash attention, KEY-SPLIT (kz=2) ------------------------
// grid (16, 32, 2): kz selects key half [kz*1024, kz*1024+1024). Partials
// merge by pure addition (no-rescale softmax). kz=0 -> Op0 (fp32 = d_out);
// kz=1 -> Op1 (bf16, reuses dead Xb region). Per-row l and xmax partials to
// lsum/xmx tables; k_comb normalizes. Q is pre-scaled, so sacc = exp2-domain
// x directly: per-score ops = xmax, xmin, clamp, exp2, add, pack.
__global__ __launch_bounds__(256) void k_attn(
    const short* __restrict__ Q, const short* __restrict__ K,
    const short* __restrict__ V, float* __restrict__ Op0,
    short* __restrict__ Op1, float* __restrict__ lsum,
    float* __restrict__ xmx, float* __restrict__ stats) {
  const int bh = blockIdx.y;
  const int q0 = blockIdx.x * 128;
  const int kz = blockIdx.z;
  const short* Qh = Q + (size_t)bh * 2048 * 64;
  const short* Kh = K + (size_t)bh * 2048 * 64;
  const short* Vh = V + (size_t)bh * 2048 * 64;  // [dh=64][s=2048]

  __shared__ __align__(16) short Ks[64 * 72];
  __shared__ __align__(16) short Vts[64 * 72];
  __shared__ __align__(16) short Ps[4][32 * 72];
  __shared__ float redA[4];

  const int t = threadIdx.x, lane = t & 63, w = t >> 6;
  const int l16 = lane & 15, quad = lane >> 4;
  const int srow = t >> 2, scol = (t & 3) * 16;
  short* myPs = &Ps[w][0];

  short8 bq8[2][2];
#pragma unroll
  for (int g = 0; g < 2; ++g) {
    const short* qsrc = Qh + (q0 + w * 32 + g * 16 + l16) * 64 + quad * 8;
    bq8[g][0] = *(const short8*)qsrc;
    bq8[g][1] = *(const short8*)(qsrc + 32);
  }

  float xmax[2] = {-1e30f, -1e30f}, xmin[2] = {1e30f, 1e30f};
  float l_lane[2] = {0.f, 0.f};
  f32x4 o_acc[2][4];
#pragma unroll
  for (int g = 0; g < 2; ++g)
#pragma unroll
    for (int jn = 0; jn < 4; ++jn) o_acc[g][jn] = {0.f, 0.f, 0.f, 0.f};
  const f32x4 zero = {0.f, 0.f, 0.f, 0.f};

  const int kt0 = kz * 16;
  short8 pk0, pk1, pv0, pv1;
  {
    const short* ksrc = Kh + (kt0 * 64 + srow) * 64 + scol;
    pk0 = *(const short8*)ksrc;
    pk1 = *(const short8*)(ksrc + 8);
    const short* vsrc = Vh + srow * 2048 + kt0 * 64 + scol;
    pv0 = *(const short8*)vsrc;
    pv1 = *(const short8*)(vsrc + 8);
  }

  for (int kt = 0; kt < 16; ++kt) {
    const int ktg = kt0 + kt;
    __syncthreads();
    *(short8*)&Ks[srow * 72 + scol] = pk0;
    *(short8*)&Ks[srow * 72 + scol + 8] = pk1;
    *(short8*)&Vts[srow * 72 + scol] = pv0;
    *(short8*)&Vts[srow * 72 + scol + 8] = pv1;
    {
      const int ktn = (kt < 15) ? ktg + 1 : ktg;
      const short* ksrc = Kh + (ktn * 64 + srow) * 64 + scol;
      pk0 = *(const short8*)ksrc;
      pk1 = *(const short8*)(ksrc + 8);
      const short* vsrc = Vh + srow * 2048 + ktn * 64 + scol;
      pv0 = *(const short8*)vsrc;
      pv1 = *(const short8*)(vsrc + 8);
    }
    __syncthreads();

    // x^T = K Q'^T (Q pre-scaled): D row = key(quad*4+r), col = q(l16)
    f32x4 sacc[2][4];
#pragma unroll
    for (int j = 0; j < 4; ++j) {
      short8 kf0 = *(const short8*)&Ks[(j * 16 + l16) * 72 + quad * 8];
      short8 kf1 = *(const short8*)&Ks[(j * 16 + l16) * 72 + 32 + quad * 8];
#pragma unroll
      for (int g = 0; g < 2; ++g)
        sacc[g][j] = MFMA(kf1, bq8[g][1], MFMA(kf0, bq8[g][0], zero));
    }

#pragma unroll
    for (int g = 0; g < 2; ++g) {
      float xm = xmax[g], xn = xmin[g], psum = l_lane[g];
#pragma unroll
      for (int j = 0; j < 4; ++j) {
        const float x0 = sacc[g][j][0], x1 = sacc[g][j][1];
        const float x2 = sacc[g][j][2], x3 = sacc[g][j][3];
        xm = fmaxf(xm, fmaxf(fmaxf(x0, x1), fmaxf(x2, x3)));
        xn = fminf(xn, fminf(fminf(x0, x1), fminf(x2, x3)));
        const float e0 = exp2f(fminf(x0, 100.f));
        const float e1 = exp2f(fminf(x1, 100.f));
        const float e2 = exp2f(fminf(x2, 100.f));
        const float e3 = exp2f(fminf(x3, 100.f));
        psum += (e0 + e1) + (e2 + e3);
        union { unsigned int u[2]; short4v s; } pk;
        pk.u[0] = f2bf2(e0, e1);
        pk.u[1] = f2bf2(e2, e3);
        *(short4v*)&myPs[(g * 16 + l16) * 72 + j * 16 + quad * 4] = pk.s;
      }
      xmax[g] = xm;
      xmin[g] = xn;
      l_lane[g] = psum;
    }
    asm volatile("" ::: "memory");  // same-wave DS pipe in-order

    // O' += P V (unnormalized)
#pragma unroll
    for (int tstep = 0; tstep < 2; ++tstep) {
      short8 ap0 = *(const short8*)&myPs[(l16)*72 + tstep * 32 + quad * 8];
      short8 ap1 = *(const short8*)&myPs[(16 + l16) * 72 + tstep * 32 + quad * 8];
#pragma unroll
      for (int jn = 0; jn < 4; ++jn) {
        short8 vf = *(const short8*)&Vts[(jn * 16 + l16) * 72 + tstep * 32 + quad * 8];
        o_acc[0][jn] = MFMA(ap0, vf, o_acc[0][jn]);
        o_acc[1][jn] = MFMA(ap1, vf, o_acc[1][jn]);
      }
    }
    asm volatile("" ::: "memory");
  }

  // cross-quad reductions; write per-row partial l and xmax tables
#pragma unroll
  for (int g = 0; g < 2; ++g) {
    float l = l_lane[g];
    l += __shfl_xor(l, 16, 64);
    l += __shfl_xor(l, 32, 64);
    float m = xmax[g];
    m = fmaxf(m, __shfl_xor(m, 16, 64));
    m = fmaxf(m, __shfl_xor(m, 32, 64));
    if (quad == 0) {
      const int row = bh * 2048 + q0 + w * 32 + g * 16 + l16;
      lsum[kz * 65536 + row] = l;
      xmx[kz * 65536 + row] = m;
    }
  }

  // write unnormalized partial O'
  const int bidx = bh >> 4, h = bh & 15;
#pragma unroll
  for (int g = 0; g < 2; ++g) {
#pragma unroll
    for (int jn = 0; jn < 4; ++jn) {
      const int d = jn * 16 + l16;
#pragma unroll
      for (int r = 0; r < 4; ++r) {
        const int s_row = q0 + w * 32 + g * 16 + quad * 4 + r;
        const size_t addr = ((size_t)(bidx * 2048 + s_row) * 1024) + h * 64 + d;
        if (kz == 0)
          Op0[addr] = o_acc[g][jn][r];
        else
          Op1[addr] = f2bf(o_acc[g][jn][r]);
      }
    }
  }

  // qk_out_max = max(|x|)/C1, wave+block reduce, atomic
  float qk = fmaxf(fmaxf(xmax[0], -xmin[0]), fmaxf(xmax[1], -xmin[1])) * INV_C1;
#pragma unroll
  for (int off = 32; off > 0; off >>= 1)
    qk = fmaxf(qk, __shfl_xor(qk, off, 64));
  if (lane == 0) redA[w] = qk;
  __syncthreads();
  if (t == 0)
    atomic_max_f32(&stats[3], fmaxf(fmaxf(redA[0], redA[1]), fmaxf(redA[2], redA[3])));
}

// ---------------- combine: O = (Op0 + Op1)/l, aw_max stat ------------------
// grid 4096 blocks (one (b,s) token each) x 256 threads (float4 each).
__global__ __launch_bounds__(256) void k_comb(
    float* __restrict__ O, const short* __restrict__ P1,
    const float* __restrict__ lsum, const float* __restrict__ xmx,
    float* __restrict__ stats) {
  __shared__ float redaw[16];
  const int t = threadIdx.x;
  const int token = blockIdx.x;  // b*2048 + s
  const int b = token >> 11, s = token & 2047;
  const int h = t >> 4;
  const int row = ((b << 4) | h) * 2048 + s;
  const float l = lsum[row] + lsum[65536 + row];
  const float linv = 1.0f / l;
  const size_t base = (size_t)token * 1024 + t * 4;
  float4 a = *(float4*)(O + base);
  short4v p = *(const short4v*)(P1 + base);
  a.x = (a.x + bf2f(p[0])) * linv;
  a.y = (a.y + bf2f(p[1])) * linv;
  a.z = (a.z + bf2f(p[2])) * linv;
  a.w = (a.w + bf2f(p[3])) * linv;
  *(float4*)(O + base) = a;
  if ((t & 15) == 0) {
    const float xm = fmaxf(xmx[row], xmx[65536 + row]);
    redaw[h] = exp2f(fminf(xm, 100.f)) * linv;  // max prob of this row
  }
  __syncthreads();
  if (t == 0) {
    float m = redaw[0];
#pragma unroll
    for (int i = 1; i < 16; ++i) m = fmaxf(m, redaw[i]);
    atomic_max_f32(&stats[4], m);
  }
}

// ---------------- finalize 6 scalar outputs (FP32) ----------------
// order: q_max, kT_max, qk_out_max, aw_max, v_max, v_out_max(=aw_max)
__global__ void k_fin(const float* __restrict__ stats, float* __restrict__ out) {
  const int i = threadIdx.x;
  if (i == 0) out[0] = stats[0];
  if (i == 1) out[1] = stats[1];
  if (i == 2) out[2] = stats[3];
  if (i == 3) out[3] = stats[4];
  if (i == 4) out[4] = stats[2];
  if (i == 5) out[5] = stats[4];
}

extern "C" void kernel_launch(void* const* d_in, const int* in_sizes, int n_in,
                              void* d_out, int out_size, void* d_ws, size_t ws_size,
                              hipStream_t stream) {
  const float* X = (const float*)d_in[0];
  const float* Wq = (const float*)d_in[1];
  const float* bq = (const float*)d_in[2];
  const float* Wk = (const float*)d_in[3];
  const float* bk = (const float*)d_in[4];
  const float* Wv = (const float*)d_in[5];
  const float* bv = (const float*)d_in[6];
  float* out = (float*)d_out;

  float* stats = (float*)d_ws;  // 8 floats; poison = atomicMax identity
  short* base = (short*)((char*)d_ws + 4096);
  short* Qb = base;             // 4096*1024 shorts
  short* Kb = base + 4194304;
  short* Vb = base + 8388608;
  short* Xb = base + 12582912;  // doubles as Op1 (bf16 partial) after k_qkv
  short* Wb = base + 16777216;  // 3*1048576 shorts; tail reused for tables
  float* lsum = (float*)(Wb);                 // 2*65536 floats (dead after k_qkv)
  float* xmx = lsum + 131072;                 // 2*65536 floats

  k_cvt<<<dim3(2048, 4), 256, 0, stream>>>(X, Wq, Wk, Wv, Xb, Wb);
  k_qkv<<<dim3(8, 32, 3), 256, 0, stream>>>(Xb, Wb, bq, bk, bv, Qb, Kb, Vb, stats);
  k_attn<<<dim3(16, 32, 2), 256, 0, stream>>>(Qb, Kb, Vb, out, Xb, lsum, xmx, stats);
  k_comb<<<4096, 256, 0, stream>>>(out, Xb, lsum, xmx, stats);
  k_fin<<<1, 64, 0, stream>>>(stats, out + 4194304);
}